// Round 3
// baseline (148.779 us; speedup 1.0000x reference)
//
#include <hip/hip_runtime.h>
#include <math.h>

#define KM 192
#define EPSF 1e-6f
#define QMIN 0.5f
#define BLK_MAIN 128

__device__ __forceinline__ float clipb(float b) {
    return fminf(fmaxf(b, 1e-4f), 1.0f - 1e-4f);
}

// ---------------- per-object argmax of q (packed u64 atomicMax) ----------------
// pack = (bits(q) << 32) | (N-1-i): q>0 so float bits are monotone; low word
// reproduces jnp.argmax first-index tiebreak (max of N-1-i == min i).
__global__ void k_argmax(const float* __restrict__ beta, const int* __restrict__ tidx,
                         unsigned long long* __restrict__ packs, int N) {
    const int e = blockIdx.y;
    __shared__ unsigned long long smax[KM];
    for (int k = threadIdx.x; k < KM; k += blockDim.x) smax[k] = 0ull;
    __syncthreads();
    const int i = blockIdx.x * blockDim.x + threadIdx.x;
    if (i < N) {
        int k = tidx[(size_t)e * N + i];
        if (k > 0) {
            float bc = clipb(beta[(size_t)e * N + i]);
            float a  = atanhf(bc);
            float q  = a * a + QMIN;
            unsigned long long pack =
                ((unsigned long long)__float_as_uint(q) << 32) |
                (unsigned long long)(unsigned)(N - 1 - i);
            atomicMax(&smax[k], pack);
        }
    }
    __syncthreads();
    for (int k = threadIdx.x; k < KM; k += blockDim.x)
        if (smax[k]) atomicMax(&packs[e * KM + k], smax[k]);
}

// ---------------- main per-hit pass + fused gather (preamble) + fused finalize ----------------
__global__ void __launch_bounds__(BLK_MAIN)
k_main(const float* __restrict__ beta, const float* __restrict__ cc,
       const float* __restrict__ pe,   const float* __restrict__ te,
       const int* __restrict__ tidx,
       const unsigned long long* __restrict__ packs,
       float* __restrict__ enm, float* __restrict__ eden,
       float* __restrict__ scal, unsigned int* __restrict__ cnt,
       float* __restrict__ out, int N, int B) {
    const int e = blockIdx.y;
    __shared__ float4 sa[KM];          // (x_alpha, y_alpha, q_alpha*valid, -)
    __shared__ float  sn[KM], sd[KM];  // energy num/den accumulators
    __shared__ float  swred[6];
    __shared__ int    lastFlag;

    // gather alpha data for this event into LDS (all L2-hit; packs carry q bits)
    for (int k = threadIdx.x; k < KM; k += BLK_MAIN) {
        unsigned long long p = packs[e * KM + k];
        float x0 = 0.f, x1 = 0.f, qv = 0.f;
        if (p) {
            int idx = N - 1 - (int)(unsigned)(p & 0xffffffffull);
            x0 = cc[((size_t)e * N + idx) * 2 + 0];
            x1 = cc[((size_t)e * N + idx) * 2 + 1];
            qv = __uint_as_float((unsigned)(p >> 32));
        }
        sa[k] = make_float4(x0, x1, qv, 0.f);
        sn[k] = 0.f; sd[k] = 0.f;
    }
    __syncthreads();

    const size_t base = (size_t)e * N;
    const int i = blockIdx.x * BLK_MAIN + threadIdx.x;
    float lv = 0.f, bn = 0.f, cn = 0.f;
    if (i < N) {
        float bc = clipb(beta[base + i]);
        float a  = atanhf(bc);
        float q  = a * a + QMIN;
        float cx = cc[(base + i) * 2 + 0];
        float cy = cc[(base + i) * 2 + 1];
        int   t  = tidx[base + i];

        // repulsive hinge over all valid objects; 4 independent accumulators
        float racc[4] = {0.f, 0.f, 0.f, 0.f};
        #pragma unroll 16
        for (int k = 0; k < KM; ++k) {
            float4 av = sa[k];
            float dx = cx - av.x, dy = cy - av.y;
            float d2 = fmaf(dx, dx, fmaf(dy, dy, EPSF));
            racc[k & 3] += fmaxf(1.f - sqrtf(d2), 0.f) * av.z;
        }
        float rep = (racc[0] + racc[1]) + (racc[2] + racc[3]);

        float att = 0.f;
        if (t > 0) {
            float4 ao = sa[t];
            float dx = cx - ao.x, dy = cy - ao.y;
            float d2e = fmaf(dx, dx, fmaf(dy, dy, EPSF));
            rep -= fmaxf(1.f - sqrtf(d2e), 0.f) * ao.z;     // remove own-object term
            att  = fmaf(dx, dx, dy * dy) * ao.z;            // attractive (no eps)

            float tev = te[base + i];
            float edv = (pe[base + i] - tev) / (tev + 1.f);
            float ad  = fabsf(edv);
            float eh  = (ad <= 2.f) ? 0.5f * ad * ad : 2.f * (ad - 1.f);
            atomicAdd(&sn[t], bc * eh);
            atomicAdd(&sd[t], bc);
        } else {
            bn = bc; cn = 1.f;
        }
        lv = q * (att + rep);
    }
    __syncthreads();

    // flush energy accumulators (skip empty slots)
    for (int k = threadIdx.x; k < KM; k += BLK_MAIN) {
        float vd = sd[k];
        if (vd != 0.f) {
            atomicAdd(&enm [e * KM + k], sn[k]);
            atomicAdd(&eden[e * KM + k], vd);
        }
    }

    // block reduction of lv / bn / cn (2 waves)
    for (int off = 32; off > 0; off >>= 1) {
        lv += __shfl_down(lv, off);
        bn += __shfl_down(bn, off);
        cn += __shfl_down(cn, off);
    }
    const int wid = threadIdx.x >> 6;
    if ((threadIdx.x & 63) == 0) {
        swred[wid] = lv; swred[2 + wid] = bn; swred[4 + wid] = cn;
    }
    __syncthreads();
    if (threadIdx.x == 0) {
        atomicAdd(&scal[e * 8 + 0], swred[0] + swred[1]);   // sum q*(att+rep)
        atomicAdd(&scal[e * 8 + 3], swred[2] + swred[3]);   // sum beta*noise
        atomicAdd(&scal[e * 8 + 4], swred[4] + swred[5]);   // noise count
    }

    // ---- last-block-done: finalize ----
    if (threadIdx.x == 0) {
        __threadfence();
        unsigned int total = gridDim.x * gridDim.y;
        unsigned int old = atomicAdd(cnt, 1u);
        lastFlag = (old == total - 1u);
    }
    __syncthreads();
    if (!lastFlag) return;

    __threadfence();
    volatile float* venm  = enm;
    volatile float* veden = eden;
    volatile float* vscal = scal;

    float tot = 0.f;
    for (int ev = 0; ev < B; ++ev) {
        float lb = 0.f, nv = 0.f, le = 0.f;
        for (int k = threadIdx.x; k < KM; k += BLK_MAIN) {
            unsigned long long p = packs[ev * KM + k];
            if (p) {
                int idx = N - 1 - (int)(unsigned)(p & 0xffffffffull);
                lb += 1.f - clipb(beta[(size_t)ev * N + idx]);
                nv += 1.f;
                le += venm[ev * KM + k] / (veden[ev * KM + k] + EPSF);
            }
        }
        for (int off = 32; off > 0; off >>= 1) {
            lb += __shfl_down(lb, off);
            nv += __shfl_down(nv, off);
            le += __shfl_down(le, off);
        }
        __syncthreads();                 // reuse sn as scratch
        if ((threadIdx.x & 63) == 0) {
            sn[threadIdx.x >> 6] = lb; sn[2 + (threadIdx.x >> 6)] = nv;
            sn[4 + (threadIdx.x >> 6)] = le;
        }
        __syncthreads();
        if (threadIdx.x == 0) {
            float lbs = sn[0] + sn[1], nvs = sn[2] + sn[3], les = sn[4] + sn[5];
            float nobj = nvs + EPSF;
            float LV = vscal[ev * 8 + 0] / (float)N;
            float LB = lbs / nobj;
            float LN = vscal[ev * 8 + 3] / (vscal[ev * 8 + 4] + EPSF);
            float LE = les / nobj;
            tot += LV + LB + LN + LE;
        }
        __syncthreads();
    }
    if (threadIdx.x == 0) out[0] = tot / (float)B;
}

extern "C" void kernel_launch(void* const* d_in, const int* in_sizes, int n_in,
                              void* d_out, int out_size, void* d_ws, size_t ws_size,
                              hipStream_t stream) {
    const int B = 4;
    const int N = in_sizes[0] / B;   // beta is [B,N,1]

    const float* beta = (const float*)d_in[0];
    const float* cc   = (const float*)d_in[1];
    const float* pe   = (const float*)d_in[2];
    const float* te   = (const float*)d_in[3];
    const int*   tidx = (const int*)  d_in[4];
    float* out = (float*)d_out;

    // workspace layout (zero-needed region contiguous at start)
    char* ws = (char*)d_ws;
    unsigned long long* packs = (unsigned long long*)ws;          // B*KM u64   @0
    float* enm  = (float*)(ws + (size_t)B * KM * 8);              // B*KM f32
    float* eden = enm + B * KM;                                   // B*KM f32
    float* scal = eden + B * KM;                                  // B*8 f32
    unsigned int* cnt = (unsigned int*)(scal + B * 8);            // 1 u32
    const size_t zeroBytes = (size_t)B * KM * 8 + (size_t)B * KM * 4 * 2
                           + (size_t)B * 8 * 4 + 64;

    (void)hipMemsetAsync(d_ws, 0, zeroBytes, stream);
    k_argmax<<<dim3((N + 255) / 256, B), dim3(256), 0, stream>>>(beta, tidx, packs, N);
    k_main<<<dim3((N + BLK_MAIN - 1) / BLK_MAIN, B), dim3(BLK_MAIN), 0, stream>>>(
        beta, cc, pe, te, tidx, packs, enm, eden, scal, cnt, out, N, B);
}

// Round 4
// 128.550 us; speedup vs baseline: 1.1574x; 1.1574x over previous
//
#include <hip/hip_runtime.h>
#include <math.h>

#define KM 192
#define NCHUNK 4
#define KCH (KM / NCHUNK)   // 48 objects per chunk-block
#define EPSF 1e-6f
#define QMIN 0.5f
#define BLK 256

__device__ __forceinline__ float clipb(float b) {
    return fminf(fmaxf(b, 1e-4f), 1.0f - 1e-4f);
}

// ---------------- per-object argmax of beta (== argmax of q, monotone) ----------------
// pack = (bits(clip(beta)) << 32) | (N-1-i): beta>0 so float bits monotone; low
// word reproduces jnp.argmax first-index tiebreak. No atanh needed here.
__global__ void __launch_bounds__(BLK)
k_argmax(const float* __restrict__ beta, const int* __restrict__ tidx,
         unsigned long long* __restrict__ packs, int N) {
    const int e = blockIdx.y;
    __shared__ unsigned long long smax[KM];
    for (int k = threadIdx.x; k < KM; k += BLK) smax[k] = 0ull;
    __syncthreads();
    const int i = blockIdx.x * BLK + threadIdx.x;
    if (i < N) {
        int k = tidx[(size_t)e * N + i];
        if (k > 0) {
            float bc = clipb(beta[(size_t)e * N + i]);
            unsigned long long pack =
                ((unsigned long long)__float_as_uint(bc) << 32) |
                (unsigned long long)(unsigned)(N - 1 - i);
            atomicMax(&smax[k], pack);
        }
    }
    __syncthreads();
    for (int k = threadIdx.x; k < KM; k += BLK)
        if (smax[k]) atomicMax(&packs[e * KM + k], smax[k]);
}

// ---------------- main: grid = (hit-block, k-chunk, event) ----------------
// Each block: partial sum of q*(att+rep) over its 256 hits x 48 objects.
// att + own-object hinge correction only in the chunk containing t.
// Energy payload + noise terms handled only by chunk 0.
__global__ void __launch_bounds__(BLK)
k_main(const float* __restrict__ beta, const float* __restrict__ cc,
       const float* __restrict__ pe,   const float* __restrict__ te,
       const int* __restrict__ tidx,
       const unsigned long long* __restrict__ packs,
       float* __restrict__ enm, float* __restrict__ eden,
       float* __restrict__ scal, int N) {
    const int e  = blockIdx.z;
    const int c  = blockIdx.y;
    const int k0 = c * KCH;
    __shared__ float4 sa[KCH];          // (x_alpha, y_alpha, q_alpha*valid, -)
    __shared__ float  sn[KM], sd[KM];   // energy num/den (chunk 0 only)
    __shared__ float  sw[12];

    if (threadIdx.x < KCH) {
        unsigned long long p = packs[e * KM + k0 + threadIdx.x];
        float x0 = 0.f, x1 = 0.f, qv = 0.f;
        if (p) {
            int idx  = N - 1 - (int)(unsigned)(p & 0xffffffffull);
            float bc = __uint_as_float((unsigned)(p >> 32));   // clipped beta_alpha
            float a  = atanhf(bc);
            qv = a * a + QMIN;
            x0 = cc[((size_t)e * N + idx) * 2 + 0];
            x1 = cc[((size_t)e * N + idx) * 2 + 1];
        }
        sa[threadIdx.x] = make_float4(x0, x1, qv, 0.f);
    }
    if (c == 0)
        for (int k = threadIdx.x; k < KM; k += BLK) { sn[k] = 0.f; sd[k] = 0.f; }
    __syncthreads();

    const size_t base = (size_t)e * N;
    const int i = blockIdx.x * BLK + threadIdx.x;
    float lv = 0.f, bn = 0.f, cn = 0.f;
    if (i < N) {
        float bc = clipb(beta[base + i]);
        float a  = atanhf(bc);
        float q  = a * a + QMIN;
        float2 cp = ((const float2*)cc)[base + i];
        int   t  = tidx[base + i];

        float racc[4] = {0.f, 0.f, 0.f, 0.f};
        #pragma unroll 12
        for (int k = 0; k < KCH; ++k) {
            float4 av = sa[k];
            float dx = cp.x - av.x, dy = cp.y - av.y;
            float d2 = fmaf(dx, dx, fmaf(dy, dy, EPSF));
            racc[k & 3] += fmaxf(1.f - sqrtf(d2), 0.f) * av.z;
        }
        float rep = (racc[0] + racc[1]) + (racc[2] + racc[3]);

        float att = 0.f;
        int tl = t - k0;
        if (t > 0 && tl >= 0 && tl < KCH) {
            float4 ao = sa[tl];
            float dx = cp.x - ao.x, dy = cp.y - ao.y;
            float d2e = fmaf(dx, dx, fmaf(dy, dy, EPSF));
            rep -= fmaxf(1.f - sqrtf(d2e), 0.f) * ao.z;   // remove own-object term
            att  = fmaf(dx, dx, dy * dy) * ao.z;          // attractive (no eps)
        }
        lv = q * (att + rep);

        if (c == 0) {
            if (t > 0) {
                float tev = te[base + i];
                float edv = (pe[base + i] - tev) / (tev + 1.f);
                float ad  = fabsf(edv);
                float eh  = (ad <= 2.f) ? 0.5f * ad * ad : 2.f * (ad - 1.f);
                atomicAdd(&sn[t], bc * eh);
                atomicAdd(&sd[t], bc);
            } else { bn = bc; cn = 1.f; }
        }
    }
    __syncthreads();

    if (c == 0) {
        for (int k = threadIdx.x; k < KM; k += BLK) {
            float vd = sd[k];
            if (vd != 0.f) {
                atomicAdd(&enm [e * KM + k], sn[k]);
                atomicAdd(&eden[e * KM + k], vd);
            }
        }
    }

    for (int off = 32; off > 0; off >>= 1) {
        lv += __shfl_down(lv, off);
        bn += __shfl_down(bn, off);
        cn += __shfl_down(cn, off);
    }
    const int wid = threadIdx.x >> 6;
    if ((threadIdx.x & 63) == 0) { sw[wid] = lv; sw[4 + wid] = bn; sw[8 + wid] = cn; }
    __syncthreads();
    if (threadIdx.x == 0) {
        atomicAdd(&scal[e * 8 + 0], (sw[0] + sw[1]) + (sw[2] + sw[3]));
        if (c == 0) {
            atomicAdd(&scal[e * 8 + 3], (sw[4] + sw[5]) + (sw[6] + sw[7]));
            atomicAdd(&scal[e * 8 + 4], (sw[8] + sw[9]) + (sw[10] + sw[11]));
        }
    }
}

// ---------------- finalize (1 block): beta_alpha comes from the packs ----------------
__global__ void __launch_bounds__(BLK)
k_fin(const float* __restrict__ enm, const float* __restrict__ eden,
      const unsigned long long* __restrict__ packs,
      const float* __restrict__ scal, float* __restrict__ out, int N, int B) {
    __shared__ float sred[12];
    float tot = 0.f;
    for (int ev = 0; ev < B; ++ev) {
        float lb = 0.f, nv = 0.f, le = 0.f;
        for (int k = threadIdx.x; k < KM; k += BLK) {
            unsigned long long p = packs[ev * KM + k];
            if (p) {
                lb += 1.f - __uint_as_float((unsigned)(p >> 32));
                nv += 1.f;
                le += enm[ev * KM + k] / (eden[ev * KM + k] + EPSF);
            }
        }
        for (int off = 32; off > 0; off >>= 1) {
            lb += __shfl_down(lb, off);
            nv += __shfl_down(nv, off);
            le += __shfl_down(le, off);
        }
        const int wid = threadIdx.x >> 6;
        if ((threadIdx.x & 63) == 0) { sred[wid] = lb; sred[4 + wid] = nv; sred[8 + wid] = le; }
        __syncthreads();
        if (threadIdx.x == 0) {
            float lbs = (sred[0] + sred[1]) + (sred[2] + sred[3]);
            float nvs = (sred[4] + sred[5]) + (sred[6] + sred[7]);
            float les = (sred[8] + sred[9]) + (sred[10] + sred[11]);
            float nobj = nvs + EPSF;
            tot += scal[ev * 8 + 0] / (float)N + lbs / nobj
                 + scal[ev * 8 + 3] / (scal[ev * 8 + 4] + EPSF) + les / nobj;
        }
        __syncthreads();
    }
    if (threadIdx.x == 0) out[0] = tot / (float)B;
}

extern "C" void kernel_launch(void* const* d_in, const int* in_sizes, int n_in,
                              void* d_out, int out_size, void* d_ws, size_t ws_size,
                              hipStream_t stream) {
    const int B = 4;
    const int N = in_sizes[0] / B;   // beta is [B,N,1]

    const float* beta = (const float*)d_in[0];
    const float* cc   = (const float*)d_in[1];
    const float* pe   = (const float*)d_in[2];
    const float* te   = (const float*)d_in[3];
    const int*   tidx = (const int*)  d_in[4];
    float* out = (float*)d_out;

    char* ws = (char*)d_ws;
    unsigned long long* packs = (unsigned long long*)ws;   // B*KM u64
    float* enm  = (float*)(ws + (size_t)B * KM * 8);       // B*KM f32
    float* eden = enm + B * KM;                            // B*KM f32
    float* scal = eden + B * KM;                           // B*8  f32
    const size_t zeroBytes = (size_t)B * KM * 8 + (size_t)B * KM * 4 * 2
                           + (size_t)B * 8 * 4;

    const int HB = (N + BLK - 1) / BLK;
    (void)hipMemsetAsync(d_ws, 0, zeroBytes, stream);
    k_argmax<<<dim3(HB, B), dim3(BLK), 0, stream>>>(beta, tidx, packs, N);
    k_main<<<dim3(HB, NCHUNK, B), dim3(BLK), 0, stream>>>(
        beta, cc, pe, te, tidx, packs, enm, eden, scal, N);
    k_fin<<<dim3(1), dim3(BLK), 0, stream>>>(enm, eden, packs, scal, out, N, B);
}